// Round 8
// baseline (14524.759 us; speedup 1.0000x reference)
//
#include <hip/hip_runtime.h>
#include <math.h>

#define NTOK 58
#define EPS 1e-5f
#define STOK 200   // trm_a scr row stride (floats)
#define SATT 68    // attb row stride
#define WT1 160    // transposed W1 row width (cols padded 150->160)
#define T1S 36     // trm_b t1l row stride: S16=9 odd -> conflict-free b128

// NOTE: every per-phase result array (a[], h4[], ...) must be read with
// STATIC indices only (ternary chains on q4/q8), else SROA demotes the
// array to scratch: round-6 measured 21GB of scratch writes from a[q4].

struct Params {
  const float *x;
  const float *mg_w,*mg_b,*mg_g,*mg_be;
  const float *dm_w,*dm_b,*dm_g,*dm_be;
  const float *al_w,*al_b,*al_g,*al_be;
  const float *mv_w,*mv_b,*mv_g,*mv_be;
  const float *sa_in_w,*sa_in_b,*sa_out_w,*sa_out_b,*san_g,*san_b;
  const float *ff_w1,*ff_b1,*ff_w2,*ff_b2,*saf_g,*saf_b;
  const float *ca_in_w,*ca_in_b,*ca_out_w,*ca_out_b,*can_g,*can_b;
  const float *pool_w,*pool_b,*pool_g,*pool_be;
  const float *z_w1,*z_b1,*z_w2,*z_b2,*z_g,*z_be;
  const float *y_w1,*y_b1,*y_w2,*y_b2,*y_g,*y_be;
  const float *head_w,*head_b;
  float *out;
};

__device__ __forceinline__ float gelu_f(float x){
  float a = 0.7978845608028654f*x*(1.0f + 0.044715f*x*x);
  float e = __expf(-2.0f*fabsf(a));
  float th = __fdividef(1.0f - e, 1.0f + e);
  th = (a < 0.0f) ? -th : th;
  return 0.5f*x*(1.0f + th);
}

__device__ __forceinline__ float wsum(float v){
  #pragma unroll
  for (int off = 32; off > 0; off >>= 1) v += __shfl_xor(v, off, 64);
  return v;
}

__device__ __forceinline__ float d4(const float4 a, const float4 b){
  return a.x*b.x + a.y*b.y + a.z*b.z + a.w*b.w;
}

template<int N4>
__device__ __forceinline__ float dotn(const float4* __restrict__ w, const float4* t){
  float a0=0.f,a1=0.f,a2=0.f,a3=0.f;
  #pragma unroll
  for (int i=0;i<N4;++i){
    float4 wa = w[i], ta = t[i];
    a0 += wa.x*ta.x; a1 += wa.y*ta.y; a2 += wa.z*ta.z; a3 += wa.w*ta.w;
  }
  return (a0+a1)+(a2+a3);
}

__device__ __forceinline__ float sel4(const float a[4], int q){
  return (q==0)?a[0]:(q==1)?a[1]:(q==2)?a[2]:a[3];
}
__device__ __forceinline__ float sel3(const float a[3], int q){
  return (q==0)?a[0]:(q==1)?a[1]:a[2];
}

// ---- prep: transpose recurrence weights to K-major ----
__global__ __launch_bounds__(256) void prep_w(const float* __restrict__ zw1, const float* __restrict__ yw1,
                                              const float* __restrict__ zw2, const float* __restrict__ yw2,
                                              float* __restrict__ ws, int B){
  const int i = blockIdx.x*256 + threadIdx.x;
  float* zt  = ws + (size_t)96*B;
  float* yt  = zt + 288*WT1;
  float* z2t = yt + 192*WT1;
  float* y2t = z2t + 150*96;
  const int NZ = 288*WT1, NY = 192*WT1, N3 = 150*96;
  if (i < NZ){
    int k = i/WT1, j = i - k*WT1;
    zt[i] = (j<150)? zw1[j*288+k] : 0.f;
  } else if (i < NZ+NY){
    int u = i-NZ; int k = u/WT1, j = u - k*WT1;
    yt[u] = (j<150)? yw1[j*192+k] : 0.f;
  } else if (i < NZ+NY+N3){
    int u = i-NZ-NY; int k = u/96, j = u - k*96;
    z2t[u] = zw2[j*150+k];
  } else if (i < NZ+NY+2*N3){
    int u = i-NZ-NY-N3; int k = u/96, j = u - k*96;
    y2t[u] = yw2[j*150+k];
  }
}

// ============ Kernel A ============
__global__ __launch_bounds__(512,4) void trm_a(Params p, float* __restrict__ xp_ws, int B){
  __shared__ __align__(16) float tok[NTOK*64];
  __shared__ __align__(16) float scr[NTOK*STOK];
  __shared__ __align__(16) float ctxv[64];
  __shared__ __align__(16) float cavec[64];
  __shared__ __align__(16) float xpv[96];
  __shared__ __align__(16) float tbuf[64];
  __shared__ float s_mean, s_rs;

  float* xrow = scr;
  float* attb = scr;

  const int b    = blockIdx.x;
  const int tid  = threadIdx.x;
  const int lane = tid & 63;
  const int wave = tid >> 6;
  const float* xb = p.x + (long)b*420;

  for (int i = tid; i < 420; i += 512) xrow[i] = xb[i];
  __syncthreads();

  for (int t = wave; t < NTOK; t += 8){
    float acc; const float *g, *be;
    if (t < 22){
      const float* w = p.mg_w + lane*6; const float* s = xrow + t*6;
      acc = p.mg_b[lane];
      #pragma unroll
      for (int f = 0; f < 6; ++f) acc += w[f]*s[f];
      g = p.mg_g; be = p.mg_be;
    } else if (t < 35){
      const float* w = p.dm_w + lane*5; const float* s = xrow + 132 + (t-22)*5;
      acc = p.dm_b[lane];
      #pragma unroll
      for (int f = 0; f < 5; ++f) acc += w[f]*s[f];
      g = p.dm_g; be = p.dm_be;
    } else {
      acc = p.al_b[lane] + p.al_w[lane]*xrow[197 + (t-35)];
      g = p.al_g; be = p.al_be;
    }
    float m = wsum(acc)*(1.f/64.f);
    float d = acc - m;
    float var = wsum(d*d)*(1.f/64.f);
    tok[t*64+lane] = gelu_f(d*rsqrtf(var+EPS)*g[lane] + be[lane]);
  }
  if (wave == 7){
    float v = p.mv_b[lane] + dotn<50>((const float4*)(p.mv_w + lane*200), (const float4*)(xrow + 220));
    float m = wsum(v)*(1.f/64.f);
    float d = v - m;
    float var = wsum(d*d)*(1.f/64.f);
    ctxv[lane] = gelu_f(d*rsqrtf(var+EPS)*p.mv_g[lane] + p.mv_be[lane]);
    tbuf[lane] = p.ca_in_b[128+lane] + dotn<16>((const float4*)(p.ca_in_w + (128+lane)*64), (const float4*)ctxv);
    cavec[lane] = p.ca_out_b[lane] + dotn<16>((const float4*)(p.ca_out_w + lane*64), (const float4*)tbuf);
  }
  __syncthreads();

  for (int pass = 0; pass < 2; ++pass){
    // ---- qkv: 512 thr = tokhalf2 x rowgroup64(x3 rows) x quadK4
    {
      const int th = tid >> 8;
      const int u  = tid & 255;
      const int rg = u >> 2, q4 = u & 3;
      const int r0 = rg*3;
      float4 wA[3][4];
      #pragma unroll
      for (int r=0;r<3;++r)
        #pragma unroll
        for (int i=0;i<4;++i)
          wA[r][i] = *(const float4*)(p.sa_in_w + (r0+r)*64 + q4*16 + i*4);
      const float bias = (q4 < 3) ? p.sa_in_b[r0+q4] : 0.f;
      for (int tt = th*29; tt < th*29+29; ++tt){
        const float4* tp = (const float4*)(tok + tt*64 + q4*16);
        float4 t4[4];
        #pragma unroll
        for (int i=0;i<4;++i) t4[i] = tp[i];
        float a[3];
        #pragma unroll
        for (int r=0;r<3;++r)
          a[r] = d4(wA[r][0],t4[0]) + d4(wA[r][1],t4[1]) + d4(wA[r][2],t4[2]) + d4(wA[r][3],t4[3]);
        #pragma unroll
        for (int r=0;r<3;++r) a[r] += __shfl_xor(a[r], 1, 64);
        #pragma unroll
        for (int r=0;r<3;++r) a[r] += __shfl_xor(a[r], 2, 64);
        if (q4 < 3) scr[tt*STOK + r0 + q4] = sel3(a, q4) + bias;   // static reads only
      }
    }
    __syncthreads();
    // ---- attention: 464 thr = (head4 x query58 x khalf2), scores recomputed
    {
      const bool act_t = tid < 464;
      int kh=0, h=0, q=0;
      float4 ac[4]; float invden = 0.f;
      if (act_t){
        const int u = tid >> 1; kh = tid & 1;
        h = u / 58; q = u - h*58;
        const int kbase = kh*29;
        float4 qv[4];
        {
          const float4* qp = (const float4*)(scr + q*STOK + h*16);
          #pragma unroll
          for (int i=0;i<4;++i) qv[i] = qp[i];
        }
        float mx = -1e30f;
        #pragma unroll
        for (int kk=0;kk<29;++kk){
          const float4* kp = (const float4*)(scr + (kbase+kk)*STOK + 64 + h*16);
          float s = d4(qv[0],kp[0]) + d4(qv[1],kp[1]) + d4(qv[2],kp[2]) + d4(qv[3],kp[3]);
          mx = fmaxf(mx, s*0.25f);
        }
        float gm = fmaxf(mx, __shfl_xor(mx, 1, 64));
        float den = 0.f;
        #pragma unroll
        for (int i=0;i<4;++i) ac[i] = make_float4(0.f,0.f,0.f,0.f);
        #pragma unroll
        for (int kk=0;kk<29;++kk){
          const float4* kp = (const float4*)(scr + (kbase+kk)*STOK + 64 + h*16);
          float s = d4(qv[0],kp[0]) + d4(qv[1],kp[1]) + d4(qv[2],kp[2]) + d4(qv[3],kp[3]);
          float e = __expf(s*0.25f - gm);
          den += e;
          const float* vp = scr + (kbase+kk)*STOK + 128 + h*16;
          #pragma unroll
          for (int i=0;i<4;++i){
            float4 v = *(const float4*)(vp + i*4);
            ac[i].x += e*v.x; ac[i].y += e*v.y; ac[i].z += e*v.z; ac[i].w += e*v.w;
          }
        }
        den += __shfl_xor(den, 1, 64);
        #pragma unroll
        for (int i=0;i<4;++i){
          ac[i].x += __shfl_xor(ac[i].x, 1, 64);
          ac[i].y += __shfl_xor(ac[i].y, 1, 64);
          ac[i].z += __shfl_xor(ac[i].z, 1, 64);
          ac[i].w += __shfl_xor(ac[i].w, 1, 64);
        }
        invden = __fdividef(1.f, den);
      }
      __syncthreads();
      if (act_t && kh == 0){
        float* op = attb + q*SATT + h*16;
        #pragma unroll
        for (int i=0;i<4;++i){
          op[i*4+0] = ac[i].x*invden; op[i*4+1] = ac[i].y*invden;
          op[i*4+2] = ac[i].z*invden; op[i*4+3] = ac[i].w*invden;
        }
      }
      __syncthreads();
    }
    // ---- out-proj + residual + fused san-LN
    {
      const int rg = lane >> 2, q4 = lane & 3;
      float4 wO[4][4];
      #pragma unroll
      for (int r=0;r<4;++r)
        #pragma unroll
        for (int i=0;i<4;++i)
          wO[r][i] = *(const float4*)(p.sa_out_w + (rg*4+r)*64 + q4*16 + i*4);
      const float bias = p.sa_out_b[lane];
      for (int t = wave; t < NTOK; t += 8){
        const float4* ap = (const float4*)(attb + t*SATT + q4*16);
        float4 a4[4];
        #pragma unroll
        for (int i=0;i<4;++i) a4[i] = ap[i];
        float a[4];
        #pragma unroll
        for (int r=0;r<4;++r)
          a[r] = d4(wO[r][0],a4[0]) + d4(wO[r][1],a4[1]) + d4(wO[r][2],a4[2]) + d4(wO[r][3],a4[3]);
        #pragma unroll
        for (int r=0;r<4;++r) a[r] += __shfl_xor(a[r], 1, 64);
        #pragma unroll
        for (int r=0;r<4;++r) a[r] += __shfl_xor(a[r], 2, 64);
        float val = tok[t*64+lane] + sel4(a, q4) + bias;   // static reads only
        float m = wsum(val)*(1.f/64.f);
        float d = val - m;
        float var = wsum(d*d)*(1.f/64.f);
        tok[t*64+lane] = d*rsqrtf(var+EPS)*p.san_g[lane] + p.san_b[lane];
      }
    }
    __syncthreads();
    // ---- ff1 64->128 + gelu
    {
      const int tq = tid >> 7, v7 = tid & 127;
      const int rg = v7 >> 2, q4 = v7 & 3;
      float4 wF[4][4];
      #pragma unroll
      for (int r=0;r<4;++r)
        #pragma unroll
        for (int i=0;i<4;++i)
          wF[r][i] = *(const float4*)(p.ff_w1 + (rg*4+r)*64 + q4*16 + i*4);
      const float bias = p.ff_b1[rg*4+q4];
      for (int t = tq; t < NTOK; t += 4){
        const float4* tp = (const float4*)(tok + t*64 + q4*16);
        float4 t4[4];
        #pragma unroll
        for (int i=0;i<4;++i) t4[i] = tp[i];
        float a[4];
        #pragma unroll
        for (int r=0;r<4;++r)
          a[r] = d4(wF[r][0],t4[0]) + d4(wF[r][1],t4[1]) + d4(wF[r][2],t4[2]) + d4(wF[r][3],t4[3]);
        #pragma unroll
        for (int r=0;r<4;++r) a[r] += __shfl_xor(a[r], 1, 64);
        #pragma unroll
        for (int r=0;r<4;++r) a[r] += __shfl_xor(a[r], 2, 64);
        scr[t*STOK + rg*4 + q4] = gelu_f(sel4(a, q4) + bias);   // static reads only
      }
    }
    __syncthreads();
    // ---- ff2 128->64 + residual
    {
      const int tq = tid >> 7, v7 = tid & 127;
      const int rg = v7 >> 3, q8 = v7 & 7;
      float4 wF[4][4];
      #pragma unroll
      for (int r=0;r<4;++r)
        #pragma unroll
        for (int i=0;i<4;++i)
          wF[r][i] = *(const float4*)(p.ff_w2 + (rg*4+r)*128 + q8*16 + i*4);
      for (int t = tq; t < NTOK; t += 4){
        const float4* hp = (const float4*)(scr + t*STOK + q8*16);
        float4 h4[4];
        #pragma unroll
        for (int i=0;i<4;++i) h4[i] = hp[i];
        float a[4];
        #pragma unroll
        for (int r=0;r<4;++r)
          a[r] = d4(wF[r][0],h4[0]) + d4(wF[r][1],h4[1]) + d4(wF[r][2],h4[2]) + d4(wF[r][3],h4[3]);
        #pragma unroll
        for (int r=0;r<4;++r) a[r] += __shfl_xor(a[r], 1, 64);
        #pragma unroll
        for (int r=0;r<4;++r) a[r] += __shfl_xor(a[r], 2, 64);
        #pragma unroll
        for (int r=0;r<4;++r) a[r] += __shfl_xor(a[r], 4, 64);
        if (q8 < 4) tok[t*64 + rg*4 + q8] += sel4(a, q8) + p.ff_b2[rg*4+q8];  // q8<4 -> static sel
      }
    }
    __syncthreads();
    for (int t = wave; t < NTOK; t += 8){ // LN saf
      float v = tok[t*64+lane];
      float m = wsum(v)*(1.f/64.f);
      float d = v-m;
      float var = wsum(d*d)*(1.f/64.f);
      tok[t*64+lane] = d*rsqrtf(var+EPS)*p.saf_g[lane] + p.saf_b[lane];
    }
    __syncthreads();
  }

  // cross-attn residual + LN can
  for (int t = wave; t < NTOK; t += 8){
    float v = tok[t*64+lane] + cavec[lane];
    float m = wsum(v)*(1.f/64.f);
    float d = v-m;
    float var = wsum(d*d)*(1.f/64.f);
    tok[t*64+lane] = d*rsqrtf(var+EPS)*p.can_g[lane] + p.can_b[lane];
  }
  __syncthreads();
  if (tid < 64){
    float s = 0.f;
    for (int t = 0; t < NTOK; ++t) s += tok[t*64 + tid];
    ctxv[tid] = s*(1.f/58.f);
  }
  __syncthreads();
  if (tid < 96) xpv[tid] = p.pool_b[tid] + dotn<16>((const float4*)(p.pool_w + tid*64), (const float4*)ctxv);
  __syncthreads();
  if (wave == 0){
    float a = xpv[lane];
    float bb = (lane < 32) ? xpv[64+lane] : 0.f;
    float m = wsum(a + bb)*(1.f/96.f);
    float da = a - m;
    float db = (lane < 32) ? (xpv[64+lane]-m) : 0.f;
    float var = wsum(da*da + db*db)*(1.f/96.f);
    if (lane==0){ s_mean=m; s_rs=rsqrtf(var+EPS); }
  }
  __syncthreads();
  if (tid < 96) xp_ws[(long)tid*B + b] = gelu_f((xpv[tid]-s_mean)*s_rs*p.pool_g[tid] + p.pool_be[tid]);
}

// ============ Kernel B: 20-step recurrence; K-major transposed weights ============
template<int M, int WS>
__device__ __forceinline__ void k4(float (&acc)[M][4], const float* __restrict__ w,
                                   const float* __restrict__ act, int jq, int sg4){
  float4 a0 = *(const float4*)(act + 0*32 + sg4);
  float4 a1 = *(const float4*)(act + 1*32 + sg4);
  float4 a2 = *(const float4*)(act + 2*32 + sg4);
  float4 a3 = *(const float4*)(act + 3*32 + sg4);
  #pragma unroll
  for (int m=0;m<M;++m){
    const int col = jq + 32*m;
    float w0 = w[0*WS+col], w1 = w[1*WS+col], w2 = w[2*WS+col], w3 = w[3*WS+col];
    acc[m][0] += w0*a0.x + w1*a1.x + w2*a2.x + w3*a3.x;
    acc[m][1] += w0*a0.y + w1*a1.y + w2*a2.y + w3*a3.y;
    acc[m][2] += w0*a0.z + w1*a1.z + w2*a2.z + w3*a3.z;
    acc[m][3] += w0*a0.w + w1*a1.w + w2*a2.w + w3*a3.w;
  }
}

__global__ __launch_bounds__(256) void trm_b(Params p, const float* __restrict__ xp,
                                             const float* __restrict__ zt, const float* __restrict__ yt,
                                             const float* __restrict__ z2t, const float* __restrict__ y2t,
                                             int B){
  __shared__ __align__(16) float xpl[96*32];
  __shared__ __align__(16) float zl [96*32];
  __shared__ __align__(16) float yl [96*32];
  __shared__ __align__(16) float t1l[150*T1S];
  __shared__ __align__(16) float psum[8*32];

  const int tid = threadIdx.x;
  const int b0 = blockIdx.x*32;
  const int jq  = tid & 31;
  const int sgi = tid >> 5;
  const int sg4 = sgi*4;
  const int part = sgi, ls = jq;

  for (int i = tid; i < 96*32; i += 256){
    int j = i >> 5, s = i & 31;
    xpl[i] = xp[(size_t)j*B + b0 + s];
    zl[i] = 0.f; yl[i] = 0.f;
  }
  __syncthreads();

  for (int step = 0; step < 20; ++step){
    // ===== z1 =====
    {
      float acc[5][4];
      #pragma unroll
      for (int m=0;m<5;++m){ acc[m][0]=acc[m][1]=acc[m][2]=acc[m][3]=0.f; }
      for (int c=0;c<24;++c) k4<5,WT1>(acc, zt + (c*4)*WT1,        xpl + c*128, jq, sg4);
      for (int c=0;c<24;++c) k4<5,WT1>(acc, zt + (96+c*4)*WT1,     yl  + c*128, jq, sg4);
      for (int c=0;c<24;++c) k4<5,WT1>(acc, zt + (192+c*4)*WT1,    zl  + c*128, jq, sg4);
      #pragma unroll
      for (int m=0;m<5;++m){
        int j = jq + 32*m;
        if (j < 150){
          float bj = p.z_b1[j];
          *(float4*)(t1l + j*T1S + sg4) = make_float4(
            gelu_f(acc[m][0]+bj), gelu_f(acc[m][1]+bj),
            gelu_f(acc[m][2]+bj), gelu_f(acc[m][3]+bj));
        }
      }
      __syncthreads();
    }
    // ===== z2 =====
    {
      float acc[3][4];
      #pragma unroll
      for (int m=0;m<3;++m){ acc[m][0]=acc[m][1]=acc[m][2]=acc[m][3]=0.f; }
      for (int c=0;c<37;++c){
        const int k = c*4;
        float4 a0 = *(const float4*)(t1l + (k+0)*T1S + sg4);
        float4 a1 = *(const float4*)(t1l + (k+1)*T1S + sg4);
        float4 a2 = *(const float4*)(t1l + (k+2)*T1S + sg4);
        float4 a3 = *(const float4*)(t1l + (k+3)*T1S + sg4);
        #pragma unroll
        for (int m=0;m<3;++m){
          const int col = jq + 32*m;
          float w0 = z2t[(k+0)*96+col], w1 = z2t[(k+1)*96+col];
          float w2 = z2t[(k+2)*96+col], w3 = z2t[(k+3)*96+col];
          acc[m][0] += w0*a0.x + w1*a1.x + w2*a2.x + w3*a3.x;
          acc[m][1] += w0*a0.y + w1*a1.y + w2*a2.y + w3*a3.y;
          acc[m][2] += w0*a0.z + w1*a1.z + w2*a2.z + w3*a3.z;
          acc[m][3] += w0*a0.w + w1*a1.w + w2*a2.w + w3*a3.w;
        }
      }
      {
        float4 a0 = *(const float4*)(t1l + 148*T1S + sg4);
        float4 a1 = *(const float4*)(t1l + 149*T1S + sg4);
        #pragma unroll
        for (int m=0;m<3;++m){
          const int col = jq + 32*m;
          float w0 = z2t[148*96+col], w1 = z2t[149*96+col];
          acc[m][0] += w0*a0.x + w1*a1.x;
          acc[m][1] += w0*a0.y + w1*a1.y;
          acc[m][2] += w0*a0.z + w1*a1.z;
          acc[m][3] += w0*a0.w + w1*a1.w;
        }
      }
      __syncthreads();
      #pragma unroll
      for (int m=0;m<3;++m){
        int j = jq + 32*m;
        float bj = p.z_b2[j];
        *(float4*)(t1l + j*T1S + sg4) = make_float4(acc[m][0]+bj, acc[m][1]+bj, acc[m][2]+bj, acc[m][3]+bj);
      }
      __syncthreads();
    }
    // ===== LN -> z += =====
    {
      float vals[12]; float s1 = 0.f;
      #pragma unroll
      for (int r=0;r<12;++r){ vals[r] = t1l[(part*12+r)*T1S + ls]; s1 += vals[r]; }
      psum[part*32+ls] = s1;
      __syncthreads();
      float m = 0.f;
      #pragma unroll
      for (int pp=0;pp<8;++pp) m += psum[pp*32+ls];
      m *= (1.f/96.f);
      float s2 = 0.f;
      #pragma unroll
      for (int r=0;r<12;++r){ float d = vals[r]-m; s2 += d*d; }
      __syncthreads();
      psum[part*32+ls] = s2;
      __syncthreads();
      float var = 0.f;
      #pragma unroll
      for (int pp=0;pp<8;++pp) var += psum[pp*32+ls];
      float rs = rsqrtf(var*(1.f/96.f)+EPS);
      #pragma unroll
      for (int r=0;r<12;++r){
        int j = part*12+r;
        zl[j*32+ls] += (vals[r]-m)*rs*p.z_g[j] + p.z_be[j];
      }
      __syncthreads();
    }
    // ===== y1 =====
    {
      float acc[5][4];
      #pragma unroll
      for (int m=0;m<5;++m){ acc[m][0]=acc[m][1]=acc[m][2]=acc[m][3]=0.f; }
      for (int c=0;c<24;++c) k4<5,WT1>(acc, yt + (c*4)*WT1,     yl + c*128, jq, sg4);
      for (int c=0;c<24;++c) k4<5,WT1>(acc, yt + (96+c*4)*WT1,  zl + c*128, jq, sg4);
      #pragma unroll
      for (int m=0;m<5;++m){
        int j = jq + 32*m;
        if (j < 150){
          float bj = p.y_b1[j];
          *(float4*)(t1l + j*T1S + sg4) = make_float4(
            gelu_f(acc[m][0]+bj), gelu_f(acc[m][1]+bj),
            gelu_f(acc[m][2]+bj), gelu_f(acc[m][3]+bj));
        }
      }
      __syncthreads();
    }
    // ===== y2 =====
    {
      float acc[3][4];
      #pragma unroll
      for (int m=0;m<3;++m){ acc[m][0]=acc[m][1]=acc[m][2]=acc[m][3]=0.f; }
      for (int c=0;c<37;++c){
        const int k = c*4;
        float4 a0 = *(const float4*)(t1l + (k+0)*T1S + sg4);
        float4 a1 = *(const float4*)(t1l + (k+1)*T1S + sg4);
        float4 a2 = *(const float4*)(t1l + (k+2)*T1S + sg4);
        float4 a3 = *(const float4*)(t1l + (k+3)*T1S + sg4);
        #pragma unroll
        for (int m=0;m<3;++m){
          const int col = jq + 32*m;
          float w0 = y2t[(k+0)*96+col], w1 = y2t[(k+1)*96+col];
          float w2 = y2t[(k+2)*96+col], w3 = y2t[(k+3)*96+col];
          acc[m][0] += w0*a0.x + w1*a1.x + w2*a2.x + w3*a3.x;
          acc[m][1] += w0*a0.y + w1*a1.y + w2*a2.y + w3*a3.y;
          acc[m][2] += w0*a0.z + w1*a1.z + w2*a2.z + w3*a3.z;
          acc[m][3] += w0*a0.w + w1*a1.w + w2*a2.w + w3*a3.w;
        }
      }
      {
        float4 a0 = *(const float4*)(t1l + 148*T1S + sg4);
        float4 a1 = *(const float4*)(t1l + 149*T1S + sg4);
        #pragma unroll
        for (int m=0;m<3;++m){
          const int col = jq + 32*m;
          float w0 = y2t[148*96+col], w1 = y2t[149*96+col];
          acc[m][0] += w0*a0.x + w1*a1.x;
          acc[m][1] += w0*a0.y + w1*a1.y;
          acc[m][2] += w0*a0.z + w1*a1.z;
          acc[m][3] += w0*a0.w + w1*a1.w;
        }
      }
      __syncthreads();
      #pragma unroll
      for (int m=0;m<3;++m){
        int j = jq + 32*m;
        float bj = p.y_b2[j];
        *(float4*)(t1l + j*T1S + sg4) = make_float4(acc[m][0]+bj, acc[m][1]+bj, acc[m][2]+bj, acc[m][3]+bj);
      }
      __syncthreads();
    }
    // ===== LN -> y += =====
    {
      float vals[12]; float s1 = 0.f;
      #pragma unroll
      for (int r=0;r<12;++r){ vals[r] = t1l[(part*12+r)*T1S + ls]; s1 += vals[r]; }
      psum[part*32+ls] = s1;
      __syncthreads();
      float m = 0.f;
      #pragma unroll
      for (int pp=0;pp<8;++pp) m += psum[pp*32+ls];
      m *= (1.f/96.f);
      float s2 = 0.f;
      #pragma unroll
      for (int r=0;r<12;++r){ float d = vals[r]-m; s2 += d*d; }
      __syncthreads();
      psum[part*32+ls] = s2;
      __syncthreads();
      float var = 0.f;
      #pragma unroll
      for (int pp=0;pp<8;++pp) var += psum[pp*32+ls];
      float rs = rsqrtf(var*(1.f/96.f)+EPS);
      #pragma unroll
      for (int r=0;r<12;++r){
        int j = part*12+r;
        yl[j*32+ls] += (vals[r]-m)*rs*p.y_g[j] + p.y_be[j];
      }
      __syncthreads();
    }
  }

  if (tid < 32){
    float acc = p.head_b[0];
    for (int j=0;j<96;++j) acc += yl[j*32+tid]*p.head_w[j];
    p.out[b0+tid] = acc;
  }
}

extern "C" void kernel_launch(void* const* d_in, const int* in_sizes, int n_in,
                              void* d_out, int out_size, void* d_ws, size_t ws_size,
                              hipStream_t stream){
  (void)n_in; (void)out_size; (void)ws_size;
  Params p;
  auto F = [&](int i){ return (const float*)d_in[i]; };
  p.x = F(0);
  p.mg_w=F(1);  p.mg_b=F(2);  p.mg_g=F(3);  p.mg_be=F(4);
  p.dm_w=F(5);  p.dm_b=F(6);  p.dm_g=F(7);  p.dm_be=F(8);
  p.al_w=F(9);  p.al_b=F(10); p.al_g=F(11); p.al_be=F(12);
  p.mv_w=F(13); p.mv_b=F(14); p.mv_g=F(15); p.mv_be=F(16);
  p.sa_in_w=F(17); p.sa_in_b=F(18); p.sa_out_w=F(19); p.sa_out_b=F(20);
  p.san_g=F(21); p.san_b=F(22);
  p.ff_w1=F(23); p.ff_b1=F(24); p.ff_w2=F(25); p.ff_b2=F(26);
  p.saf_g=F(27); p.saf_b=F(28);
  p.ca_in_w=F(29); p.ca_in_b=F(30); p.ca_out_w=F(31); p.ca_out_b=F(32);
  p.can_g=F(33); p.can_b=F(34);
  p.pool_w=F(35); p.pool_b=F(36); p.pool_g=F(37); p.pool_be=F(38);
  p.z_w1=F(39); p.z_b1=F(40); p.z_w2=F(41); p.z_b2=F(42); p.z_g=F(43); p.z_be=F(44);
  p.y_w1=F(45); p.y_b1=F(46); p.y_w2=F(47); p.y_b2=F(48); p.y_g=F(49); p.y_be=F(50);
  p.head_w=F(51); p.head_b=F(52);
  p.out = (float*)d_out;

  int B = in_sizes[0]/420;
  float* ws = (float*)d_ws;
  float* xw  = ws;                       // [96][B]
  float* zt  = ws + (size_t)96*B;        // [288][160]
  float* yt  = zt + 288*WT1;             // [192][160]
  float* z2t = yt + 192*WT1;             // [150][96]
  float* y2t = z2t + 150*96;             // [150][96]

  const int prep_n = 288*WT1 + 192*WT1 + 2*150*96;
  hipLaunchKernelGGL(prep_w, dim3((prep_n+255)/256), dim3(256), 0, stream,
                     p.z_w1, p.y_w1, p.z_w2, p.y_w2, ws, B);
  hipLaunchKernelGGL(trm_a, dim3(B), dim3(512), 0, stream, p, xw, B);
  hipLaunchKernelGGL(trm_b, dim3(B/32), dim3(256), 0, stream, p,
                     (const float*)xw, (const float*)zt, (const float*)yt,
                     (const float*)z2t, (const float*)y2t, B);
}

// Round 9
// 5991.824 us; speedup vs baseline: 2.4241x; 2.4241x over previous
//
#include <hip/hip_runtime.h>
#include <math.h>

#define NTOK 58
#define EPS 1e-5f
#define STOK 200   // trm_a scr row stride (floats)
#define SATT 68    // attb row stride
#define WT1 160    // transposed W1 row width (cols padded 150->160)
#define T1S 36     // trm_b t1l row stride: S16=9 odd -> conflict-free b128

// trm_a below is the byte-exact round-3 submission (benched: 5535us, WRITE 1.5GB,
// VALUBusy 60%). Do NOT restructure the attention phase: the two-pass recompute
// variant produced 22GB of scratch traffic (rounds 6/8) regardless of sel3/sel4.

struct Params {
  const float *x;
  const float *mg_w,*mg_b,*mg_g,*mg_be;
  const float *dm_w,*dm_b,*dm_g,*dm_be;
  const float *al_w,*al_b,*al_g,*al_be;
  const float *mv_w,*mv_b,*mv_g,*mv_be;
  const float *sa_in_w,*sa_in_b,*sa_out_w,*sa_out_b,*san_g,*san_b;
  const float *ff_w1,*ff_b1,*ff_w2,*ff_b2,*saf_g,*saf_b;
  const float *ca_in_w,*ca_in_b,*ca_out_w,*ca_out_b,*can_g,*can_b;
  const float *pool_w,*pool_b,*pool_g,*pool_be;
  const float *z_w1,*z_b1,*z_w2,*z_b2,*z_g,*z_be;
  const float *y_w1,*y_b1,*y_w2,*y_b2,*y_g,*y_be;
  const float *head_w,*head_b;
  float *out;
};

__device__ __forceinline__ float gelu_f(float x){
  float a = 0.7978845608028654f*x*(1.0f + 0.044715f*x*x);
  float e = __expf(-2.0f*fabsf(a));
  float th = __fdividef(1.0f - e, 1.0f + e);
  th = (a < 0.0f) ? -th : th;
  return 0.5f*x*(1.0f + th);
}

__device__ __forceinline__ float wsum(float v){
  #pragma unroll
  for (int off = 32; off > 0; off >>= 1) v += __shfl_xor(v, off, 64);
  return v;
}

__device__ __forceinline__ float d4(const float4 a, const float4 b){
  return a.x*b.x + a.y*b.y + a.z*b.z + a.w*b.w;
}

template<int N4>
__device__ __forceinline__ float dotn(const float4* __restrict__ w, const float4* t){
  float a0=0.f,a1=0.f,a2=0.f,a3=0.f;
  #pragma unroll
  for (int i=0;i<N4;++i){
    float4 wa = w[i], ta = t[i];
    a0 += wa.x*ta.x; a1 += wa.y*ta.y; a2 += wa.z*ta.z; a3 += wa.w*ta.w;
  }
  return (a0+a1)+(a2+a3);
}

// ---- prep: transpose recurrence weights to K-major ----
__global__ __launch_bounds__(256) void prep_w(const float* __restrict__ zw1, const float* __restrict__ yw1,
                                              const float* __restrict__ zw2, const float* __restrict__ yw2,
                                              float* __restrict__ ws, int B){
  const int i = blockIdx.x*256 + threadIdx.x;
  float* zt  = ws + (size_t)96*B;
  float* yt  = zt + 288*WT1;
  float* z2t = yt + 192*WT1;
  float* y2t = z2t + 150*96;
  const int NZ = 288*WT1, NY = 192*WT1, N3 = 150*96;
  if (i < NZ){
    int k = i/WT1, j = i - k*WT1;
    zt[i] = (j<150)? zw1[j*288+k] : 0.f;
  } else if (i < NZ+NY){
    int u = i-NZ; int k = u/WT1, j = u - k*WT1;
    yt[u] = (j<150)? yw1[j*192+k] : 0.f;
  } else if (i < NZ+NY+N3){
    int u = i-NZ-NY; int k = u/96, j = u - k*96;
    z2t[u] = zw2[j*150+k];
  } else if (i < NZ+NY+2*N3){
    int u = i-NZ-NY-N3; int k = u/96, j = u - k*96;
    y2t[u] = yw2[j*150+k];
  }
}

// ============ Kernel A: tokenizer + 2x self-attn + cross + pool -> xp ============
__global__ __launch_bounds__(512,4) void trm_a(Params p, float* __restrict__ xp_ws, int B){
  __shared__ __align__(16) float tok[NTOK*64];     // 14.8KB
  __shared__ __align__(16) float scr[NTOK*STOK];   // 46.4KB: xrow / qkv / attb / ff-hidden overlays
  __shared__ __align__(16) float ctxv[64];
  __shared__ __align__(16) float cavec[64];
  __shared__ __align__(16) float xpv[96];
  __shared__ __align__(16) float tbuf[64];
  __shared__ float s_mean, s_rs;

  float* xrow = scr;   // [420] overlay, dead after tokenizer/ctx
  float* attb = scr;   // [58*SATT] overlay, live only between attention & out-proj

  const int b    = blockIdx.x;
  const int tid  = threadIdx.x;
  const int lane = tid & 63;
  const int wave = tid >> 6;
  const float* xb = p.x + (long)b*420;

  for (int i = tid; i < 420; i += 512) xrow[i] = xb[i];
  __syncthreads();

  // tokenizer linear + fused LN + gelu: wave owns token, lane = channel
  for (int t = wave; t < NTOK; t += 8){
    float acc; const float *g, *be;
    if (t < 22){
      const float* w = p.mg_w + lane*6; const float* s = xrow + t*6;
      acc = p.mg_b[lane];
      #pragma unroll
      for (int f = 0; f < 6; ++f) acc += w[f]*s[f];
      g = p.mg_g; be = p.mg_be;
    } else if (t < 35){
      const float* w = p.dm_w + lane*5; const float* s = xrow + 132 + (t-22)*5;
      acc = p.dm_b[lane];
      #pragma unroll
      for (int f = 0; f < 5; ++f) acc += w[f]*s[f];
      g = p.dm_g; be = p.dm_be;
    } else {
      acc = p.al_b[lane] + p.al_w[lane]*xrow[197 + (t-35)];
      g = p.al_g; be = p.al_be;
    }
    float m = wsum(acc)*(1.f/64.f);
    float d = acc - m;
    float var = wsum(d*d)*(1.f/64.f);
    tok[t*64+lane] = gelu_f(d*rsqrtf(var+EPS)*g[lane] + be[lane]);
  }
  // ctx chain on wave 7: pre-LN dot, fused LN+gelu, then cross-attn const vec
  if (wave == 7){
    float v = p.mv_b[lane] + dotn<50>((const float4*)(p.mv_w + lane*200), (const float4*)(xrow + 220));
    float m = wsum(v)*(1.f/64.f);
    float d = v - m;
    float var = wsum(d*d)*(1.f/64.f);
    ctxv[lane] = gelu_f(d*rsqrtf(var+EPS)*p.mv_g[lane] + p.mv_be[lane]);
    tbuf[lane] = p.ca_in_b[128+lane] + dotn<16>((const float4*)(p.ca_in_w + (128+lane)*64), (const float4*)ctxv);
    cavec[lane] = p.ca_out_b[lane] + dotn<16>((const float4*)(p.ca_out_w + lane*64), (const float4*)tbuf);
  }
  __syncthreads();   // tok complete; xrow dead -> scr free

  for (int pass = 0; pass < 2; ++pass){
    // ---- qkv: 512 thr = tokhalf2 x rowgroup64(x3 rows) x quadK4(16 each)
    {
      const int th = tid >> 8;
      const int u  = tid & 255;
      const int rg = u >> 2, q4 = u & 3;
      const int r0 = rg*3;
      float4 wA[3][4];
      #pragma unroll
      for (int r=0;r<3;++r)
        #pragma unroll
        for (int i=0;i<4;++i)
          wA[r][i] = *(const float4*)(p.sa_in_w + (r0+r)*64 + q4*16 + i*4);
      const float bias = (q4 < 3) ? p.sa_in_b[r0+q4] : 0.f;
      for (int tt = th*29; tt < th*29+29; ++tt){
        const float4* tp = (const float4*)(tok + tt*64 + q4*16);
        float4 t4[4];
        #pragma unroll
        for (int i=0;i<4;++i) t4[i] = tp[i];
        float a[3];
        #pragma unroll
        for (int r=0;r<3;++r)
          a[r] = d4(wA[r][0],t4[0]) + d4(wA[r][1],t4[1]) + d4(wA[r][2],t4[2]) + d4(wA[r][3],t4[3]);
        #pragma unroll
        for (int r=0;r<3;++r) a[r] += __shfl_xor(a[r], 1, 64);
        #pragma unroll
        for (int r=0;r<3;++r) a[r] += __shfl_xor(a[r], 2, 64);
        if (q4 < 3) scr[tt*STOK + r0 + q4] = a[q4] + bias;
      }
    }
    __syncthreads();
    // ---- attention: 464 thr = (head4 x query58 x khalf2)
    {
      const bool act_t = tid < 464;
      int kh=0, h=0, q=0;
      float4 ac[4]; float invden = 0.f;
      if (act_t){
        const int u = tid >> 1; kh = tid & 1;
        h = u / 58; q = u - h*58;
        const int kbase = kh*29;
        float4 qv[4];
        {
          const float4* qp = (const float4*)(scr + q*STOK + h*16);
          #pragma unroll
          for (int i=0;i<4;++i) qv[i] = qp[i];
        }
        float sc[29]; float mx = -1e30f;
        #pragma unroll
        for (int kk=0;kk<29;++kk){
          const float4* kp = (const float4*)(scr + (kbase+kk)*STOK + 64 + h*16);
          float s = d4(qv[0],kp[0]) + d4(qv[1],kp[1]) + d4(qv[2],kp[2]) + d4(qv[3],kp[3]);
          s *= 0.25f;
          sc[kk] = s; mx = fmaxf(mx, s);
        }
        float gm = fmaxf(mx, __shfl_xor(mx, 1, 64));
        float den = 0.f;
        #pragma unroll
        for (int i=0;i<4;++i) ac[i] = make_float4(0.f,0.f,0.f,0.f);
        #pragma unroll
        for (int kk=0;kk<29;++kk){
          float e = __expf(sc[kk] - gm);
          den += e;
          const float4* vp = (const float4*)(scr + (kbase+kk)*STOK + 128 + h*16);
          #pragma unroll
          for (int i=0;i<4;++i){
            float4 v = vp[i];
            ac[i].x += e*v.x; ac[i].y += e*v.y; ac[i].z += e*v.z; ac[i].w += e*v.w;
          }
        }
        den += __shfl_xor(den, 1, 64);
        #pragma unroll
        for (int i=0;i<4;++i){
          ac[i].x += __shfl_xor(ac[i].x, 1, 64);
          ac[i].y += __shfl_xor(ac[i].y, 1, 64);
          ac[i].z += __shfl_xor(ac[i].z, 1, 64);
          ac[i].w += __shfl_xor(ac[i].w, 1, 64);
        }
        invden = __fdividef(1.f, den);
      }
      __syncthreads();   // all scr(q,k,v) reads done -> safe to overlay attb
      if (act_t && kh == 0){
        float* op = attb + q*SATT + h*16;
        #pragma unroll
        for (int i=0;i<4;++i){
          op[i*4+0] = ac[i].x*invden; op[i*4+1] = ac[i].y*invden;
          op[i*4+2] = ac[i].z*invden; op[i*4+3] = ac[i].w*invden;
        }
      }
      __syncthreads();
    }
    // ---- out-proj + residual + FUSED san-LN: wave = tokslot, lane = channel
    {
      const int rg = lane >> 2, q4 = lane & 3;
      float4 wO[4][4];
      #pragma unroll
      for (int r=0;r<4;++r)
        #pragma unroll
        for (int i=0;i<4;++i)
          wO[r][i] = *(const float4*)(p.sa_out_w + (rg*4+r)*64 + q4*16 + i*4);
      const float bias = p.sa_out_b[lane];
      for (int t = wave; t < NTOK; t += 8){
        const float4* ap = (const float4*)(attb + t*SATT + q4*16);
        float4 a4[4];
        #pragma unroll
        for (int i=0;i<4;++i) a4[i] = ap[i];
        float a[4];
        #pragma unroll
        for (int r=0;r<4;++r)
          a[r] = d4(wO[r][0],a4[0]) + d4(wO[r][1],a4[1]) + d4(wO[r][2],a4[2]) + d4(wO[r][3],a4[3]);
        #pragma unroll
        for (int r=0;r<4;++r) a[r] += __shfl_xor(a[r], 1, 64);
        #pragma unroll
        for (int r=0;r<4;++r) a[r] += __shfl_xor(a[r], 2, 64);
        float val = tok[t*64+lane] + a[q4] + bias;
        float m = wsum(val)*(1.f/64.f);
        float d = val - m;
        float var = wsum(d*d)*(1.f/64.f);
        tok[t*64+lane] = d*rsqrtf(var+EPS)*p.san_g[lane] + p.san_b[lane];
      }
    }
    __syncthreads();
    // ---- ff1 64->128 + gelu: 512 thr = (tq4 x rg32 x q4)
    {
      const int tq = tid >> 7, v7 = tid & 127;
      const int rg = v7 >> 2, q4 = v7 & 3;
      float4 wF[4][4];
      #pragma unroll
      for (int r=0;r<4;++r)
        #pragma unroll
        for (int i=0;i<4;++i)
          wF[r][i] = *(const float4*)(p.ff_w1 + (rg*4+r)*64 + q4*16 + i*4);
      const float bias = p.ff_b1[rg*4+q4];
      for (int t = tq; t < NTOK; t += 4){
        const float4* tp = (const float4*)(tok + t*64 + q4*16);
        float4 t4[4];
        #pragma unroll
        for (int i=0;i<4;++i) t4[i] = tp[i];
        float a[4];
        #pragma unroll
        for (int r=0;r<4;++r)
          a[r] = d4(wF[r][0],t4[0]) + d4(wF[r][1],t4[1]) + d4(wF[r][2],t4[2]) + d4(wF[r][3],t4[3]);
        #pragma unroll
        for (int r=0;r<4;++r) a[r] += __shfl_xor(a[r], 1, 64);
        #pragma unroll
        for (int r=0;r<4;++r) a[r] += __shfl_xor(a[r], 2, 64);
        scr[t*STOK + rg*4 + q4] = gelu_f(a[q4] + bias);
      }
    }
    __syncthreads();
    // ---- ff2 128->64 + residual: (tq4 x rg16 x q8)
    {
      const int tq = tid >> 7, v7 = tid & 127;
      const int rg = v7 >> 3, q8 = v7 & 7;
      float4 wF[4][4];
      #pragma unroll
      for (int r=0;r<4;++r)
        #pragma unroll
        for (int i=0;i<4;++i)
          wF[r][i] = *(const float4*)(p.ff_w2 + (rg*4+r)*128 + q8*16 + i*4);
      for (int t = tq; t < NTOK; t += 4){
        const float4* hp = (const float4*)(scr + t*STOK + q8*16);
        float4 h4[4];
        #pragma unroll
        for (int i=0;i<4;++i) h4[i] = hp[i];
        float a[4];
        #pragma unroll
        for (int r=0;r<4;++r)
          a[r] = d4(wF[r][0],h4[0]) + d4(wF[r][1],h4[1]) + d4(wF[r][2],h4[2]) + d4(wF[r][3],h4[3]);
        #pragma unroll
        for (int r=0;r<4;++r) a[r] += __shfl_xor(a[r], 1, 64);
        #pragma unroll
        for (int r=0;r<4;++r) a[r] += __shfl_xor(a[r], 2, 64);
        #pragma unroll
        for (int r=0;r<4;++r) a[r] += __shfl_xor(a[r], 4, 64);
        if (q8 < 4) tok[t*64 + rg*4 + q8] += a[q8] + p.ff_b2[rg*4+q8];
      }
    }
    __syncthreads();
    for (int t = wave; t < NTOK; t += 8){ // LN saf
      float v = tok[t*64+lane];
      float m = wsum(v)*(1.f/64.f);
      float d = v-m;
      float var = wsum(d*d)*(1.f/64.f);
      tok[t*64+lane] = d*rsqrtf(var+EPS)*p.saf_g[lane] + p.saf_b[lane];
    }
    __syncthreads();
  }

  // cross-attn residual (constant vector) + LN can
  for (int t = wave; t < NTOK; t += 8){
    float v = tok[t*64+lane] + cavec[lane];
    float m = wsum(v)*(1.f/64.f);
    float d = v-m;
    float var = wsum(d*d)*(1.f/64.f);
    tok[t*64+lane] = d*rsqrtf(var+EPS)*p.can_g[lane] + p.can_b[lane];
  }
  __syncthreads();
  if (tid < 64){ // pool mean over tokens
    float s = 0.f;
    for (int t = 0; t < NTOK; ++t) s += tok[t*64 + tid];
    ctxv[tid] = s*(1.f/58.f);
  }
  __syncthreads();
  if (tid < 96) xpv[tid] = p.pool_b[tid] + dotn<16>((const float4*)(p.pool_w + tid*64), (const float4*)ctxv);
  __syncthreads();
  if (wave == 0){ // LN over 96
    float a = xpv[lane];
    float bb = (lane < 32) ? xpv[64+lane] : 0.f;
    float m = wsum(a + bb)*(1.f/96.f);
    float da = a - m;
    float db = (lane < 32) ? (xpv[64+lane]-m) : 0.f;
    float var = wsum(da*da + db*db)*(1.f/96.f);
    if (lane==0){ s_mean=m; s_rs=rsqrtf(var+EPS); }
  }
  __syncthreads();
  if (tid < 96) xp_ws[(long)tid*B + b] = gelu_f((xpv[tid]-s_mean)*s_rs*p.pool_g[tid] + p.pool_be[tid]);
}

// ============ Kernel B: 20-step recurrence; K-major transposed weights ============
template<int M, int WS>
__device__ __forceinline__ void k4(float (&acc)[M][4], const float* __restrict__ w,
                                   const float* __restrict__ act, int jq, int sg4){
  float4 a0 = *(const float4*)(act + 0*32 + sg4);
  float4 a1 = *(const float4*)(act + 1*32 + sg4);
  float4 a2 = *(const float4*)(act + 2*32 + sg4);
  float4 a3 = *(const float4*)(act + 3*32 + sg4);
  #pragma unroll
  for (int m=0;m<M;++m){
    const int col = jq + 32*m;
    float w0 = w[0*WS+col], w1 = w[1*WS+col], w2 = w[2*WS+col], w3 = w[3*WS+col];
    acc[m][0] += w0*a0.x + w1*a1.x + w2*a2.x + w3*a3.x;
    acc[m][1] += w0*a0.y + w1*a1.y + w2*a2.y + w3*a3.y;
    acc[m][2] += w0*a0.z + w1*a1.z + w2*a2.z + w3*a3.z;
    acc[m][3] += w0*a0.w + w1*a1.w + w2*a2.w + w3*a3.w;
  }
}

__global__ __launch_bounds__(256) void trm_b(Params p, const float* __restrict__ xp,
                                             const float* __restrict__ zt, const float* __restrict__ yt,
                                             const float* __restrict__ z2t, const float* __restrict__ y2t,
                                             int B){
  __shared__ __align__(16) float xpl[96*32];
  __shared__ __align__(16) float zl [96*32];
  __shared__ __align__(16) float yl [96*32];
  __shared__ __align__(16) float t1l[150*T1S];
  __shared__ __align__(16) float psum[8*32];

  const int tid = threadIdx.x;
  const int b0 = blockIdx.x*32;
  const int jq  = tid & 31;
  const int sgi = tid >> 5;
  const int sg4 = sgi*4;
  const int part = sgi, ls = jq;

  for (int i = tid; i < 96*32; i += 256){
    int j = i >> 5, s = i & 31;
    xpl[i] = xp[(size_t)j*B + b0 + s];
    zl[i] = 0.f; yl[i] = 0.f;
  }
  __syncthreads();

  for (int step = 0; step < 20; ++step){
    // ===== z1 =====
    {
      float acc[5][4];
      #pragma unroll
      for (int m=0;m<5;++m){ acc[m][0]=acc[m][1]=acc[m][2]=acc[m][3]=0.f; }
      for (int c=0;c<24;++c) k4<5,WT1>(acc, zt + (c*4)*WT1,        xpl + c*128, jq, sg4);
      for (int c=0;c<24;++c) k4<5,WT1>(acc, zt + (96+c*4)*WT1,     yl  + c*128, jq, sg4);
      for (int c=0;c<24;++c) k4<5,WT1>(acc, zt + (192+c*4)*WT1,    zl  + c*128, jq, sg4);
      #pragma unroll
      for (int m=0;m<5;++m){
        int j = jq + 32*m;
        if (j < 150){
          float bj = p.z_b1[j];
          *(float4*)(t1l + j*T1S + sg4) = make_float4(
            gelu_f(acc[m][0]+bj), gelu_f(acc[m][1]+bj),
            gelu_f(acc[m][2]+bj), gelu_f(acc[m][3]+bj));
        }
      }
      __syncthreads();
    }
    // ===== z2 =====
    {
      float acc[3][4];
      #pragma unroll
      for (int m=0;m<3;++m){ acc[m][0]=acc[m][1]=acc[m][2]=acc[m][3]=0.f; }
      for (int c=0;c<37;++c){
        const int k = c*4;
        float4 a0 = *(const float4*)(t1l + (k+0)*T1S + sg4);
        float4 a1 = *(const float4*)(t1l + (k+1)*T1S + sg4);
        float4 a2 = *(const float4*)(t1l + (k+2)*T1S + sg4);
        float4 a3 = *(const float4*)(t1l + (k+3)*T1S + sg4);
        #pragma unroll
        for (int m=0;m<3;++m){
          const int col = jq + 32*m;
          float w0 = z2t[(k+0)*96+col], w1 = z2t[(k+1)*96+col];
          float w2 = z2t[(k+2)*96+col], w3 = z2t[(k+3)*96+col];
          acc[m][0] += w0*a0.x + w1*a1.x + w2*a2.x + w3*a3.x;
          acc[m][1] += w0*a0.y + w1*a1.y + w2*a2.y + w3*a3.y;
          acc[m][2] += w0*a0.z + w1*a1.z + w2*a2.z + w3*a3.z;
          acc[m][3] += w0*a0.w + w1*a1.w + w2*a2.w + w3*a3.w;
        }
      }
      {
        float4 a0 = *(const float4*)(t1l + 148*T1S + sg4);
        float4 a1 = *(const float4*)(t1l + 149*T1S + sg4);
        #pragma unroll
        for (int m=0;m<3;++m){
          const int col = jq + 32*m;
          float w0 = z2t[148*96+col], w1 = z2t[149*96+col];
          acc[m][0] += w0*a0.x + w1*a1.x;
          acc[m][1] += w0*a0.y + w1*a1.y;
          acc[m][2] += w0*a0.z + w1*a1.z;
          acc[m][3] += w0*a0.w + w1*a1.w;
        }
      }
      __syncthreads();
      #pragma unroll
      for (int m=0;m<3;++m){
        int j = jq + 32*m;
        float bj = p.z_b2[j];
        *(float4*)(t1l + j*T1S + sg4) = make_float4(acc[m][0]+bj, acc[m][1]+bj, acc[m][2]+bj, acc[m][3]+bj);
      }
      __syncthreads();
    }
    // ===== LN -> z += =====
    {
      float vals[12]; float s1 = 0.f;
      #pragma unroll
      for (int r=0;r<12;++r){ vals[r] = t1l[(part*12+r)*T1S + ls]; s1 += vals[r]; }
      psum[part*32+ls] = s1;
      __syncthreads();
      float m = 0.f;
      #pragma unroll
      for (int pp=0;pp<8;++pp) m += psum[pp*32+ls];
      m *= (1.f/96.f);
      float s2 = 0.f;
      #pragma unroll
      for (int r=0;r<12;++r){ float d = vals[r]-m; s2 += d*d; }
      __syncthreads();
      psum[part*32+ls] = s2;
      __syncthreads();
      float var = 0.f;
      #pragma unroll
      for (int pp=0;pp<8;++pp) var += psum[pp*32+ls];
      float rs = rsqrtf(var*(1.f/96.f)+EPS);
      #pragma unroll
      for (int r=0;r<12;++r){
        int j = part*12+r;
        zl[j*32+ls] += (vals[r]-m)*rs*p.z_g[j] + p.z_be[j];
      }
      __syncthreads();
    }
    // ===== y1 =====
    {
      float acc[5][4];
      #pragma unroll
      for (int m=0;m<5;++m){ acc[m][0]=acc[m][1]=acc[m][2]=acc[m][3]=0.f; }
      for (int c=0;c<24;++c) k4<5,WT1>(acc, yt + (c*4)*WT1,     yl + c*128, jq, sg4);
      for (int c=0;c<24;++c) k4<5,WT1>(acc, yt + (96+c*4)*WT1,  zl + c*128, jq, sg4);
      #pragma unroll
      for (int m=0;m<5;++m){
        int j = jq + 32*m;
        if (j < 150){
          float bj = p.y_b1[j];
          *(float4*)(t1l + j*T1S + sg4) = make_float4(
            gelu_f(acc[m][0]+bj), gelu_f(acc[m][1]+bj),
            gelu_f(acc[m][2]+bj), gelu_f(acc[m][3]+bj));
        }
      }
      __syncthreads();
    }
    // ===== y2 =====
    {
      float acc[3][4];
      #pragma unroll
      for (int m=0;m<3;++m){ acc[m][0]=acc[m][1]=acc[m][2]=acc[m][3]=0.f; }
      for (int c=0;c<37;++c){
        const int k = c*4;
        float4 a0 = *(const float4*)(t1l + (k+0)*T1S + sg4);
        float4 a1 = *(const float4*)(t1l + (k+1)*T1S + sg4);
        float4 a2 = *(const float4*)(t1l + (k+2)*T1S + sg4);
        float4 a3 = *(const float4*)(t1l + (k+3)*T1S + sg4);
        #pragma unroll
        for (int m=0;m<3;++m){
          const int col = jq + 32*m;
          float w0 = y2t[(k+0)*96+col], w1 = y2t[(k+1)*96+col];
          float w2 = y2t[(k+2)*96+col], w3 = y2t[(k+3)*96+col];
          acc[m][0] += w0*a0.x + w1*a1.x + w2*a2.x + w3*a3.x;
          acc[m][1] += w0*a0.y + w1*a1.y + w2*a2.y + w3*a3.y;
          acc[m][2] += w0*a0.z + w1*a1.z + w2*a2.z + w3*a3.z;
          acc[m][3] += w0*a0.w + w1*a1.w + w2*a2.w + w3*a3.w;
        }
      }
      {
        float4 a0 = *(const float4*)(t1l + 148*T1S + sg4);
        float4 a1 = *(const float4*)(t1l + 149*T1S + sg4);
        #pragma unroll
        for (int m=0;m<3;++m){
          const int col = jq + 32*m;
          float w0 = y2t[148*96+col], w1 = y2t[149*96+col];
          acc[m][0] += w0*a0.x + w1*a1.x;
          acc[m][1] += w0*a0.y + w1*a1.y;
          acc[m][2] += w0*a0.z + w1*a1.z;
          acc[m][3] += w0*a0.w + w1*a1.w;
        }
      }
      __syncthreads();
      #pragma unroll
      for (int m=0;m<3;++m){
        int j = jq + 32*m;
        float bj = p.y_b2[j];
        *(float4*)(t1l + j*T1S + sg4) = make_float4(acc[m][0]+bj, acc[m][1]+bj, acc[m][2]+bj, acc[m][3]+bj);
      }
      __syncthreads();
    }
    // ===== LN -> y += =====
    {
      float vals[12]; float s1 = 0.f;
      #pragma unroll
      for (int r=0;r<12;++r){ vals[r] = t1l[(part*12+r)*T1S + ls]; s1 += vals[r]; }
      psum[part*32+ls] = s1;
      __syncthreads();
      float m = 0.f;
      #pragma unroll
      for (int pp=0;pp<8;++pp) m += psum[pp*32+ls];
      m *= (1.f/96.f);
      float s2 = 0.f;
      #pragma unroll
      for (int r=0;r<12;++r){ float d = vals[r]-m; s2 += d*d; }
      __syncthreads();
      psum[part*32+ls] = s2;
      __syncthreads();
      float var = 0.f;
      #pragma unroll
      for (int pp=0;pp<8;++pp) var += psum[pp*32+ls];
      float rs = rsqrtf(var*(1.f/96.f)+EPS);
      #pragma unroll
      for (int r=0;r<12;++r){
        int j = part*12+r;
        yl[j*32+ls] += (vals[r]-m)*rs*p.y_g[j] + p.y_be[j];
      }
      __syncthreads();
    }
  }

  if (tid < 32){
    float acc = p.head_b[0];
    for (int j=0;j<96;++j) acc += yl[j*32+tid]*p.head_w[j];
    p.out[b0+tid] = acc;
  }
}

extern "C" void kernel_launch(void* const* d_in, const int* in_sizes, int n_in,
                              void* d_out, int out_size, void* d_ws, size_t ws_size,
                              hipStream_t stream){
  (void)n_in; (void)out_size; (void)ws_size;
  Params p;
  auto F = [&](int i){ return (const float*)d_in[i]; };
  p.x = F(0);
  p.mg_w=F(1);  p.mg_b=F(2);  p.mg_g=F(3);  p.mg_be=F(4);
  p.dm_w=F(5);  p.dm_b=F(6);  p.dm_g=F(7);  p.dm_be=F(8);
  p.al_w=F(9);  p.al_b=F(10); p.al_g=F(11); p.al_be=F(12);
  p.mv_w=F(13); p.mv_b=F(14); p.mv_g=F(15); p.mv_be=F(16);
  p.sa_in_w=F(17); p.sa_in_b=F(18); p.sa_out_w=F(19); p.sa_out_b=F(20);
  p.san_g=F(21); p.san_b=F(22);
  p.ff_w1=F(23); p.ff_b1=F(24); p.ff_w2=F(25); p.ff_b2=F(26);
  p.saf_g=F(27); p.saf_b=F(28);
  p.ca_in_w=F(29); p.ca_in_b=F(30); p.ca_out_w=F(31); p.ca_out_b=F(32);
  p.can_g=F(33); p.can_b=F(34);
  p.pool_w=F(35); p.pool_b=F(36); p.pool_g=F(37); p.pool_be=F(38);
  p.z_w1=F(39); p.z_b1=F(40); p.z_w2=F(41); p.z_b2=F(42); p.z_g=F(43); p.z_be=F(44);
  p.y_w1=F(45); p.y_b1=F(46); p.y_w2=F(47); p.y_b2=F(48); p.y_g=F(49); p.y_be=F(50);
  p.head_w=F(51); p.head_b=F(52);
  p.out = (float*)d_out;

  int B = in_sizes[0]/420;
  float* ws = (float*)d_ws;
  float* xw  = ws;                       // [96][B]
  float* zt  = ws + (size_t)96*B;        // [288][160]
  float* yt  = zt + 288*WT1;             // [192][160]
  float* z2t = yt + 192*WT1;             // [150][96]
  float* y2t = z2t + 150*96;             // [150][96]

  const int prep_n = 288*WT1 + 192*WT1 + 2*150*96;
  hipLaunchKernelGGL(prep_w, dim3((prep_n+255)/256), dim3(256), 0, stream,
                     p.z_w1, p.y_w1, p.z_w2, p.y_w2, ws, B);
  hipLaunchKernelGGL(trm_a, dim3(B), dim3(512), 0, stream, p, xw, B);
  hipLaunchKernelGGL(trm_b, dim3(B/32), dim3(256), 0, stream, p,
                     (const float*)xw, (const float*)zt, (const float*)yt,
                     (const float*)z2t, (const float*)y2t, B);
}